// Round 11
// baseline (332.267 us; speedup 1.0000x reference)
//
#include <hip/hip_runtime.h>
#include <hip/hip_bf16.h>
#include <cstdint>
#include <cstddef>

typedef __bf16 bf16x8 __attribute__((ext_vector_type(8)));
typedef float f32x4 __attribute__((ext_vector_type(4)));
typedef unsigned int uintx4 __attribute__((ext_vector_type(4)));

#define CONV_SCALE 0.014731391274719738f   // 1/sqrt(512*9)
#define MOD_SCALE  0.044194173824159216f   // 1/sqrt(512)

__device__ __forceinline__ unsigned short f2bf(float v) {
  unsigned int u = __float_as_uint(v);
  return (unsigned short)((u + 0x7FFFu + ((u >> 16) & 1u)) >> 16);  // RNE
}

__device__ __forceinline__ void gload16(const void* g, void* l) {
  __builtin_amdgcn_global_load_lds(
      (const __attribute__((address_space(1))) unsigned int*)g,
      (__attribute__((address_space(3))) unsigned int*)l, 16, 0, 0);
}

// prep1: blocks 0..511 -> wT + wsq ; blocks 512..543 -> s (modulation)
__global__ void k_prep1(const float* __restrict__ style,
                        const float* __restrict__ mod_w,
                        const float* __restrict__ mod_b,
                        const float* __restrict__ weight,
                        float* __restrict__ s,
                        unsigned short* __restrict__ wT,
                        float* __restrict__ wsq) {
  __shared__ float lds[4608];
  int t = threadIdx.x;             // 256
  if (blockIdx.x < 512) {
    int co = blockIdx.x;
    const float* w = weight + (size_t)co * 4608;
    #pragma unroll
    for (int i = 0; i < 18; ++i) lds[t + i * 256] = w[t + i * 256];
    __syncthreads();
    for (int i = t; i < 576; i += 256) {
      int tap = i / 64, c8 = (i & 63) * 8;
      union { uintx4 v; unsigned short us[8]; } pk;
      #pragma unroll
      for (int j = 0; j < 8; ++j) pk.us[j] = f2bf(lds[(c8 + j) * 9 + tap]);
      *(uintx4*)(wT + ((size_t)tap * 512 + co) * 512 + c8) = pk.v;
    }
    for (int ci = t; ci < 512; ci += 256) {
      float a = 0.f;
      #pragma unroll
      for (int tap = 0; tap < 9; ++tap) { float v = lds[ci * 9 + tap]; a += v * v; }
      wsq[co * 512 + ci] = a * (CONV_SCALE * CONV_SCALE);
    }
  } else {
    int blk = blockIdx.x - 512;    // 0..31
    int b = blk >> 2, ch = blk & 3;
    int ci = ch * 128 + (t >> 1), half = t & 1;
    const float* st = style + b * 512 + half * 256;
    const float* mw = mod_w + (size_t)ci * 512 + half * 256;
    float acc = 0.f;
    #pragma unroll 8
    for (int k = 0; k < 256; k += 4) {
      f32x4 a = *(const f32x4*)(st + k);
      f32x4 m = *(const f32x4*)(mw + k);
      acc += a[0] * m[0] + a[1] * m[1] + a[2] * m[2] + a[3] * m[3];
    }
    acc += __shfl_xor(acc, 1);
    if (half == 0) s[b * 512 + ci] = acc * MOD_SCALE + mod_b[ci];
  }
}

// prep2: blocks 0..2047 -> xT transpose+modulate ; blocks 2048..2063 -> demod
__global__ void k_prep2(const float* __restrict__ x,
                        const float* __restrict__ s,
                        const float* __restrict__ wsq,
                        unsigned short* __restrict__ xT,
                        float* __restrict__ demod) {
  __shared__ float lds[128][68];
  int t = threadIdx.x;             // 256
  int id = blockIdx.x;
  if (id < 2048) {
    int cc = id & 3, h = (id >> 2) & 63, b = id >> 8;
    int w4 = (t & 15) * 4, rr = t >> 4;
    #pragma unroll
    for (int i = 0; i < 8; ++i) {
      int ci = i * 16 + rr;
      *(f32x4*)&lds[ci][w4] =
          *(const f32x4*)&x[(((size_t)(b * 512 + cc * 128 + ci)) * 64 + h) * 64 + w4];
    }
    __syncthreads();
    int pos = t >> 2, c4 = t & 3;
    #pragma unroll
    for (int q = 0; q < 4; ++q) {
      int cb = q * 32 + c4 * 8;
      union { uintx4 v; unsigned short us[8]; } pk;
      #pragma unroll
      for (int j = 0; j < 8; ++j) {
        int ci = cb + j;
        pk.us[j] = f2bf(lds[ci][pos] * s[b * 512 + cc * 128 + ci]);
      }
      *(uintx4*)(xT + (((size_t)(b * 64 + h)) * 64 + pos) * 512 + cc * 128 + cb) = pk.v;
    }
  } else {
    int blk = id - 2048;           // 0..15
    int b = blk >> 1;
    int co = (blk & 1) * 256 + t;
    const float* wq = wsq + (size_t)co * 512;
    const float* sb = s + b * 512;
    float acc = 0.f;
    #pragma unroll 4
    for (int ci = 0; ci < 512; ci += 4) {
      f32x4 q = *(const f32x4*)(wq + ci);
      f32x4 v = *(const f32x4*)(sb + ci);
      acc += q[0] * v[0] * v[0] + q[1] * v[1] * v[1] + q[2] * v[2] * v[2] + q[3] * v[3] * v[3];
    }
    demod[b * 512 + co] = rsqrtf(acc + 1e-8f);
  }
}

// Implicit-GEMM conv — R10 skeleton (3-tap phases, gates {3,5,5}, ring-9, 48
// barriers) with TWO intra-phase changes:
//  (1) NO s_setprio anywhere (it fences the scheduler between read and MFMA
//      clusters; lockstep waves -> no arbitration benefit anyway).
//  (2) Explicit 1-tap-deep software pipeline INSIDE each phase (no asm/builtin
//      between reads and MFMAs): rd(t0); rd(t1); MF(t0); rd(t2); MF(t1); MF(t2)
//      -> tap T+1's ds_reads hide under tap T's 32-MFMA stream.
// No read crosses a barrier; hazard set identical to R10.
__global__ __launch_bounds__(512, 2) void k_conv(
    const unsigned short* __restrict__ xT,   // [B][64][64][512]
    const unsigned short* __restrict__ wT,   // [9][512][512]
    const float* __restrict__ demod,         // [B][512]
    float* __restrict__ out) {               // [B][512][64][64]
  extern __shared__ __align__(16) char lds_raw[];
  char* xb0   = lds_raw;              // 42240
  char* xb1   = lds_raw + 42240;      // 42240
  char* wring = lds_raw + 84480;      // 9 * 8192 = 73728
  char* trash = lds_raw + 158208;     // 1024

  const int id  = blockIdx.x;         // 256
  const int g_ord = (id & 7) * 32 + (id >> 3);   // XCD-contiguous ordering
  const int co_t  = g_ord >> 6;       // 0..3
  const int slice = g_ord & 63;       // 0..63
  const int b   = slice >> 3;
  const int h_t = slice & 7;

  const int t = threadIdx.x;          // 512
  const int lane = t & 63, wv = t >> 6;   // 8 waves
  const int h0  = h_t * 8;
  const int co0 = co_t * 128;
  const int l15 = lane & 15, kg = lane >> 4;
  const int wrow = wv & 3;            // row-pair within tile
  const int wco  = wv >> 2;           // co half (0/1)

  // zero both x buffers (halo cols 0/65 + OOB rows stay zero forever)
  {
    uintx4 z = {0u, 0u, 0u, 0u};
    for (int i = t; i < 5280; i += 512) ((uintx4*)lds_raw)[i] = z;
  }
  __syncthreads();

  // ---- x stage: issue j in 0..39 (j = r*4 + k), 1 KB per wave-issue
  auto xstage = [&](int j, int ccs, char* xbuf) {
    int r = j >> 2, k = j & 3;
    int hh = h0 - 1 + r;
    int hc = ((unsigned)hh < 64u) ? hh : 0;
    int p = r * 66 + 1 + k * 16 + (lane >> 2);
    const void* src = xT + (((size_t)(b * 64 + hc)) * 64 + k * 16 + (lane >> 2)) * 512
                      + ccs * 32 + (((lane & 3) ^ ((p >> 1) & 3)) << 3);
    void* dst = ((unsigned)hh < 64u) ? (void*)(xbuf + (r * 66 + 1 + k * 16) * 64)
                                     : (void*)trash;
    gload16(src, dst);
  };
  // ---- w stage for (chunk cc2, tap tap2) into ring slot = tap2 (1 KB/wave-issue)
  auto wstage = [&](int cc2, int tap2) {
    bool valid = (cc2 < 16);
    int cs = valid ? cc2 : 15;
    int row0 = wv * 16;
    int row = row0 + (lane >> 2);
    const void* src = wT + ((size_t)tap2 * 512 + co0 + row) * 512
                      + cs * 32 + (((lane & 3) ^ ((row >> 1) & 3)) << 3);
    void* dst = valid ? (void*)(wring + tap2 * 8192 + row0 * 64) : (void*)trash;
    gload16(src, dst);
  };

  f32x4 acc[4][2][4] = {};            // [m(co)][r(row)][n(w)]

  auto rdA = [&](bf16x8* af, int T) {
    #pragma unroll
    for (int m = 0; m < 4; ++m) {
      int row = wco * 64 + m * 16 + l15;
      af[m] = *(const bf16x8*)(wring + T * 8192 + row * 64 + ((kg ^ ((row >> 1) & 3)) << 4));
    }
  };
  auto rdB = [&](bf16x8 (*bfr)[4], const char* xcur, int dh, int dw) {
    #pragma unroll
    for (int r = 0; r < 2; ++r)
      #pragma unroll
      for (int n = 0; n < 4; ++n) {
        int p = (2 * wrow + r + dh) * 66 + n * 16 + l15 + dw;
        bfr[r][n] = *(const bf16x8*)(xcur + p * 64 + ((kg ^ ((p >> 1) & 3)) << 4));
      }
  };
  auto mf = [&](const bf16x8* af, const bf16x8 (*bfr)[4]) {
    #pragma unroll
    for (int m = 0; m < 4; ++m)
      #pragma unroll
      for (int r = 0; r < 2; ++r)
        #pragma unroll
        for (int n = 0; n < 4; ++n)
          acc[m][r][n] = __builtin_amdgcn_mfma_f32_16x16x32_bf16(af[m], bfr[r][n], acc[m][r][n], 0, 0, 0);
  };

  // prologue: w slots 0..5 (6/wave), x chunk 0 (5/wave); single full drain.
  #pragma unroll
  for (int i = 0; i < 6; ++i) wstage(0, i);
  #pragma unroll
  for (int i = 0; i < 5; ++i) xstage(wv * 5 + i, 0, xb0);
  asm volatile("s_waitcnt vmcnt(0)" ::: "memory");
  __syncthreads();

  #pragma unroll 1
  for (int cc = 0; cc < 16; ++cc) {
    const char* xcur = (cc & 1) ? xb1 : xb0;
    char* xnxt = (cc & 1) ? xb0 : xb1;
    const int ccs = (cc + 1) & 15;    // wrapped src chunk for next-x (cc=15: dummy)
    bf16x8 a0[4], a1[4], a2[4], b0[2][4], b1[2][4], b2[2][4];

    // ---- phase 0 (dh=0): reads slots {0,1,2}; stages w(cc,6..8) + x(2)
    asm volatile("s_waitcnt vmcnt(3)" ::: "memory");
    __builtin_amdgcn_s_barrier();
    xstage(wv, ccs, xnxt); xstage(wv + 8, ccs, xnxt);
    wstage(cc, 6); wstage(cc, 7); wstage(cc, 8);
    rdA(a0, 0); rdB(b0, xcur, 0, 0);
    rdA(a1, 1); rdB(b1, xcur, 0, 1);
    mf(a0, b0);
    rdA(a2, 2); rdB(b2, xcur, 0, 2);
    mf(a1, b1);
    mf(a2, b2);

    // ---- phase 1 (dh=1): reads slots {3,4,5}; stages w(cc+1,0..2) + x(2)
    asm volatile("s_waitcnt vmcnt(5)" ::: "memory");
    __builtin_amdgcn_s_barrier();
    xstage(wv + 16, ccs, xnxt); xstage(wv + 24, ccs, xnxt);
    wstage(cc + 1, 0); wstage(cc + 1, 1); wstage(cc + 1, 2);
    rdA(a0, 3); rdB(b0, xcur, 1, 0);
    rdA(a1, 4); rdB(b1, xcur, 1, 1);
    mf(a0, b0);
    rdA(a2, 5); rdB(b2, xcur, 1, 2);
    mf(a1, b1);
    mf(a2, b2);

    // ---- phase 2 (dh=2): reads slots {6,7,8}; stages x(1, FIRST) + w(cc+1,3..5)
    asm volatile("s_waitcnt vmcnt(5)" ::: "memory");
    __builtin_amdgcn_s_barrier();
    xstage(wv + 32, ccs, xnxt);
    wstage(cc + 1, 3); wstage(cc + 1, 4); wstage(cc + 1, 5);
    rdA(a0, 6); rdB(b0, xcur, 2, 0);
    rdA(a1, 7); rdB(b1, xcur, 2, 1);
    mf(a0, b0);
    rdA(a2, 8); rdB(b2, xcur, 2, 2);
    mf(a1, b1);
    mf(a2, b2);
  }

  // epilogue: out[b][co][h][w] = acc * conv_scale * demod[b][co]
  #pragma unroll
  for (int m = 0; m < 4; ++m) {
    #pragma unroll
    for (int q = 0; q < 4; ++q) {
      int co = co0 + wco * 64 + m * 16 + kg * 4 + q;
      float scl = CONV_SCALE * demod[b * 512 + co];
      #pragma unroll
      for (int r = 0; r < 2; ++r) {
        int h_out = h0 + 2 * wrow + r;
        #pragma unroll
        for (int n = 0; n < 4; ++n) {
          out[(((size_t)(b * 512 + co)) * 64 + h_out) * 64 + n * 16 + l15] = acc[m][r][n][q] * scl;
        }
      }
    }
  }
}

extern "C" void kernel_launch(void* const* d_in, const int* in_sizes, int n_in,
                              void* d_out, int out_size, void* d_ws, size_t ws_size,
                              hipStream_t stream) {
  const float* x      = (const float*)d_in[0];  // (8,512,64,64)
  const float* style  = (const float*)d_in[1];  // (8,512)
  const float* weight = (const float*)d_in[2];  // (1,512,512,3,3)
  const float* mod_w  = (const float*)d_in[3];  // (512,512)
  const float* mod_b  = (const float*)d_in[4];  // (512,)
  float* out = (float*)d_out;

  // workspace layout (~39.4 MB)
  char* ws = (char*)d_ws;
  unsigned short* xT = (unsigned short*)ws;               // 33,554,432 B
  unsigned short* wT = (unsigned short*)(ws + 33554432);  //  4,718,592 B
  float* s     = (float*)(ws + 38273024);                 //     16,384 B
  float* wsq   = (float*)(ws + 38289408);                 //  1,048,576 B
  float* demod = (float*)(ws + 39337984);                 //     16,384 B

  static int lds_set = 0;
  if (!lds_set) {
    (void)hipFuncSetAttribute((const void*)k_conv,
                              hipFuncAttributeMaxDynamicSharedMemorySize, 159232);
    lds_set = 1;
  }

  hipLaunchKernelGGL(k_prep1, dim3(544),  dim3(256), 0, stream,
                     style, mod_w, mod_b, weight, s, wT, wsq);
  hipLaunchKernelGGL(k_prep2, dim3(2064), dim3(256), 0, stream, x, s, wsq, xT, demod);
  hipLaunchKernelGGL(k_conv,  dim3(256),  dim3(512), 159232, stream, xT, wT, demod, out);
}

// Round 12
// 289.310 us; speedup vs baseline: 1.1485x; 1.1485x over previous
//
#include <hip/hip_runtime.h>
#include <hip/hip_bf16.h>
#include <cstdint>
#include <cstddef>

typedef __bf16 bf16x8 __attribute__((ext_vector_type(8)));
typedef float f32x4 __attribute__((ext_vector_type(4)));
typedef unsigned int uintx4 __attribute__((ext_vector_type(4)));

#define CONV_SCALE 0.014731391274719738f   // 1/sqrt(512*9)
#define MOD_SCALE  0.044194173824159216f   // 1/sqrt(512)

__device__ __forceinline__ unsigned short f2bf(float v) {
  unsigned int u = __float_as_uint(v);
  return (unsigned short)((u + 0x7FFFu + ((u >> 16) & 1u)) >> 16);  // RNE
}

__device__ __forceinline__ void gload16(const void* g, void* l) {
  __builtin_amdgcn_global_load_lds(
      (const __attribute__((address_space(1))) unsigned int*)g,
      (__attribute__((address_space(3))) unsigned int*)l, 16, 0, 0);
}

// prep1: blocks 0..511 -> wT + wsq ; blocks 512..543 -> s (modulation)
__global__ void k_prep1(const float* __restrict__ style,
                        const float* __restrict__ mod_w,
                        const float* __restrict__ mod_b,
                        const float* __restrict__ weight,
                        float* __restrict__ s,
                        unsigned short* __restrict__ wT,
                        float* __restrict__ wsq) {
  __shared__ float lds[4608];
  int t = threadIdx.x;             // 256
  if (blockIdx.x < 512) {
    int co = blockIdx.x;
    const float* w = weight + (size_t)co * 4608;
    #pragma unroll
    for (int i = 0; i < 18; ++i) lds[t + i * 256] = w[t + i * 256];
    __syncthreads();
    for (int i = t; i < 576; i += 256) {
      int tap = i / 64, c8 = (i & 63) * 8;
      union { uintx4 v; unsigned short us[8]; } pk;
      #pragma unroll
      for (int j = 0; j < 8; ++j) pk.us[j] = f2bf(lds[(c8 + j) * 9 + tap]);
      *(uintx4*)(wT + ((size_t)tap * 512 + co) * 512 + c8) = pk.v;
    }
    for (int ci = t; ci < 512; ci += 256) {
      float a = 0.f;
      #pragma unroll
      for (int tap = 0; tap < 9; ++tap) { float v = lds[ci * 9 + tap]; a += v * v; }
      wsq[co * 512 + ci] = a * (CONV_SCALE * CONV_SCALE);
    }
  } else {
    int blk = blockIdx.x - 512;    // 0..31
    int b = blk >> 2, ch = blk & 3;
    int ci = ch * 128 + (t >> 1), half = t & 1;
    const float* st = style + b * 512 + half * 256;
    const float* mw = mod_w + (size_t)ci * 512 + half * 256;
    float acc = 0.f;
    #pragma unroll 8
    for (int k = 0; k < 256; k += 4) {
      f32x4 a = *(const f32x4*)(st + k);
      f32x4 m = *(const f32x4*)(mw + k);
      acc += a[0] * m[0] + a[1] * m[1] + a[2] * m[2] + a[3] * m[3];
    }
    acc += __shfl_xor(acc, 1);
    if (half == 0) s[b * 512 + ci] = acc * MOD_SCALE + mod_b[ci];
  }
}

// prep2: blocks 0..2047 -> xT transpose+modulate ; blocks 2048..2063 -> demod
__global__ void k_prep2(const float* __restrict__ x,
                        const float* __restrict__ s,
                        const float* __restrict__ wsq,
                        unsigned short* __restrict__ xT,
                        float* __restrict__ demod) {
  __shared__ float lds[128][68];
  int t = threadIdx.x;             // 256
  int id = blockIdx.x;
  if (id < 2048) {
    int cc = id & 3, h = (id >> 2) & 63, b = id >> 8;
    int w4 = (t & 15) * 4, rr = t >> 4;
    #pragma unroll
    for (int i = 0; i < 8; ++i) {
      int ci = i * 16 + rr;
      *(f32x4*)&lds[ci][w4] =
          *(const f32x4*)&x[(((size_t)(b * 512 + cc * 128 + ci)) * 64 + h) * 64 + w4];
    }
    __syncthreads();
    int pos = t >> 2, c4 = t & 3;
    #pragma unroll
    for (int q = 0; q < 4; ++q) {
      int cb = q * 32 + c4 * 8;
      union { uintx4 v; unsigned short us[8]; } pk;
      #pragma unroll
      for (int j = 0; j < 8; ++j) {
        int ci = cb + j;
        pk.us[j] = f2bf(lds[ci][pos] * s[b * 512 + cc * 128 + ci]);
      }
      *(uintx4*)(xT + (((size_t)(b * 64 + h)) * 64 + pos) * 512 + cc * 128 + cb) = pk.v;
    }
  } else {
    int blk = id - 2048;           // 0..15
    int b = blk >> 1;
    int co = (blk & 1) * 256 + t;
    const float* wq = wsq + (size_t)co * 512;
    const float* sb = s + b * 512;
    float acc = 0.f;
    #pragma unroll 4
    for (int ci = 0; ci < 512; ci += 4) {
      f32x4 q = *(const f32x4*)(wq + ci);
      f32x4 v = *(const f32x4*)(sb + ci);
      acc += q[0] * v[0] * v[0] + q[1] * v[1] * v[1] + q[2] * v[2] * v[2] + q[3] * v[3] * v[3];
    }
    demod[b * 512 + co] = rsqrtf(acc + 1e-8f);
  }
}

// Implicit-GEMM conv — R10 skeleton VERBATIM (3-tap phases, gates {3,5,5},
// ring-9 slot=tap, 48 barriers, same staging order) with a register-BOUNDED
// intra-phase pipeline and NO scheduler fences:
//  - no s_setprio (unmodeled side effects = fences between read/MFMA clusters;
//    null for lockstep waves per m190)
//  - per tap, 4 n-groups of 8 MFMAs; x-frags rotate through TWO buffers g0/g1
//    (rdG(n+1) issued between MFMA groups), w-frags rotate afA/afB (rdA(next
//    tap) under the last group). Peak live frags = 48 VGPR (same as R6) -> no
//    spill (R11's 3-set version spilled: 473MB FETCH).
//  - g0/g1 WAR rotation bounds how far the scheduler can hoist reads.
// No read crosses a barrier; hazard/gate accounting identical to R10 (passed).
__global__ __launch_bounds__(512, 2) void k_conv(
    const unsigned short* __restrict__ xT,   // [B][64][64][512]
    const unsigned short* __restrict__ wT,   // [9][512][512]
    const float* __restrict__ demod,         // [B][512]
    float* __restrict__ out) {               // [B][512][64][64]
  extern __shared__ __align__(16) char lds_raw[];
  char* xb0   = lds_raw;              // 42240
  char* xb1   = lds_raw + 42240;      // 42240
  char* wring = lds_raw + 84480;      // 9 * 8192 = 73728
  char* trash = lds_raw + 158208;     // 1024

  const int id  = blockIdx.x;         // 256
  const int g_ord = (id & 7) * 32 + (id >> 3);   // XCD-contiguous ordering
  const int co_t  = g_ord >> 6;       // 0..3
  const int slice = g_ord & 63;       // 0..63
  const int b   = slice >> 3;
  const int h_t = slice & 7;

  const int t = threadIdx.x;          // 512
  const int lane = t & 63, wv = t >> 6;   // 8 waves
  const int h0  = h_t * 8;
  const int co0 = co_t * 128;
  const int l15 = lane & 15, kg = lane >> 4;
  const int wrow = wv & 3;            // row-pair within tile
  const int wco  = wv >> 2;           // co half (0/1)

  // zero both x buffers (halo cols 0/65 + OOB rows stay zero forever)
  {
    uintx4 z = {0u, 0u, 0u, 0u};
    for (int i = t; i < 5280; i += 512) ((uintx4*)lds_raw)[i] = z;
  }
  __syncthreads();

  // ---- x stage: issue j in 0..39 (j = r*4 + k), 1 KB per wave-issue
  auto xstage = [&](int j, int ccs, char* xbuf) {
    int r = j >> 2, k = j & 3;
    int hh = h0 - 1 + r;
    int hc = ((unsigned)hh < 64u) ? hh : 0;
    int p = r * 66 + 1 + k * 16 + (lane >> 2);
    const void* src = xT + (((size_t)(b * 64 + hc)) * 64 + k * 16 + (lane >> 2)) * 512
                      + ccs * 32 + (((lane & 3) ^ ((p >> 1) & 3)) << 3);
    void* dst = ((unsigned)hh < 64u) ? (void*)(xbuf + (r * 66 + 1 + k * 16) * 64)
                                     : (void*)trash;
    gload16(src, dst);
  };
  // ---- w stage for (chunk cc2, tap tap2) into ring slot = tap2 (1 KB/wave-issue)
  auto wstage = [&](int cc2, int tap2) {
    bool valid = (cc2 < 16);
    int cs = valid ? cc2 : 15;
    int row0 = wv * 16;
    int row = row0 + (lane >> 2);
    const void* src = wT + ((size_t)tap2 * 512 + co0 + row) * 512
                      + cs * 32 + (((lane & 3) ^ ((row >> 1) & 3)) << 3);
    void* dst = valid ? (void*)(wring + tap2 * 8192 + row0 * 64) : (void*)trash;
    gload16(src, dst);
  };

  f32x4 acc[4][2][4] = {};            // [m(co)][r(row)][n(w)]

  auto rdA = [&](bf16x8* af, int T) {
    #pragma unroll
    for (int m = 0; m < 4; ++m) {
      int row = wco * 64 + m * 16 + l15;
      af[m] = *(const bf16x8*)(wring + T * 8192 + row * 64 + ((kg ^ ((row >> 1) & 3)) << 4));
    }
  };
  auto rdG = [&](bf16x8* g, const char* xcur, int dh, int dw, int n) {
    #pragma unroll
    for (int r = 0; r < 2; ++r) {
      int p = (2 * wrow + r + dh) * 66 + n * 16 + l15 + dw;
      g[r] = *(const bf16x8*)(xcur + p * 64 + ((kg ^ ((p >> 1) & 3)) << 4));
    }
  };
  auto mfg = [&](const bf16x8* af, const bf16x8* g, int n) {
    #pragma unroll
    for (int m = 0; m < 4; ++m)
      #pragma unroll
      for (int r = 0; r < 2; ++r)
        acc[m][r][n] = __builtin_amdgcn_mfma_f32_16x16x32_bf16(af[m], g[r], acc[m][r][n], 0, 0, 0);
  };

  // one phase = 3 taps (dh fixed, dw=0,1,2), n-group pipelined, 2-buffer rotation
  auto phase = [&](const char* xcur, int s0, int dh) {
    bf16x8 afA[4], afB[4], g0[2], g1[2];
    rdA(afA, s0);     rdG(g0, xcur, dh, 0, 0);
    rdG(g1, xcur, dh, 0, 1);                     mfg(afA, g0, 0);
    rdG(g0, xcur, dh, 0, 2);                     mfg(afA, g1, 1);
    rdG(g1, xcur, dh, 0, 3);                     mfg(afA, g0, 2);
    rdA(afB, s0 + 1); rdG(g0, xcur, dh, 1, 0);   mfg(afA, g1, 3);
    rdG(g1, xcur, dh, 1, 1);                     mfg(afB, g0, 0);
    rdG(g0, xcur, dh, 1, 2);                     mfg(afB, g1, 1);
    rdG(g1, xcur, dh, 1, 3);                     mfg(afB, g0, 2);
    rdA(afA, s0 + 2); rdG(g0, xcur, dh, 2, 0);   mfg(afB, g1, 3);
    rdG(g1, xcur, dh, 2, 1);                     mfg(afA, g0, 0);
    rdG(g0, xcur, dh, 2, 2);                     mfg(afA, g1, 1);
    rdG(g1, xcur, dh, 2, 3);                     mfg(afA, g0, 2);
                                                 mfg(afA, g1, 3);
  };

  // prologue: w slots 0..5 (6/wave), x chunk 0 (5/wave); single full drain.
  #pragma unroll
  for (int i = 0; i < 6; ++i) wstage(0, i);
  #pragma unroll
  for (int i = 0; i < 5; ++i) xstage(wv * 5 + i, 0, xb0);
  asm volatile("s_waitcnt vmcnt(0)" ::: "memory");
  __syncthreads();

  #pragma unroll 1
  for (int cc = 0; cc < 16; ++cc) {
    const char* xcur = (cc & 1) ? xb1 : xb0;
    char* xnxt = (cc & 1) ? xb0 : xb1;
    const int ccs = (cc + 1) & 15;    // wrapped src chunk for next-x (cc=15: dummy)

    // ---- phase 0 (dh=0): reads slots {0,1,2}; stages x(2) + w(cc,6..8)
    asm volatile("s_waitcnt vmcnt(3)" ::: "memory");
    __builtin_amdgcn_s_barrier();
    xstage(wv, ccs, xnxt); xstage(wv + 8, ccs, xnxt);
    wstage(cc, 6); wstage(cc, 7); wstage(cc, 8);
    phase(xcur, 0, 0);

    // ---- phase 1 (dh=1): reads slots {3,4,5}; stages x(2) + w(cc+1,0..2)
    asm volatile("s_waitcnt vmcnt(5)" ::: "memory");
    __builtin_amdgcn_s_barrier();
    xstage(wv + 16, ccs, xnxt); xstage(wv + 24, ccs, xnxt);
    wstage(cc + 1, 0); wstage(cc + 1, 1); wstage(cc + 1, 2);
    phase(xcur, 3, 1);

    // ---- phase 2 (dh=2): reads slots {6,7,8}; stages x(1, FIRST) + w(cc+1,3..5)
    asm volatile("s_waitcnt vmcnt(5)" ::: "memory");
    __builtin_amdgcn_s_barrier();
    xstage(wv + 32, ccs, xnxt);
    wstage(cc + 1, 3); wstage(cc + 1, 4); wstage(cc + 1, 5);
    phase(xcur, 6, 2);
  }

  // epilogue: out[b][co][h][w] = acc * conv_scale * demod[b][co]
  #pragma unroll
  for (int m = 0; m < 4; ++m) {
    #pragma unroll
    for (int q = 0; q < 4; ++q) {
      int co = co0 + wco * 64 + m * 16 + kg * 4 + q;
      float scl = CONV_SCALE * demod[b * 512 + co];
      #pragma unroll
      for (int r = 0; r < 2; ++r) {
        int h_out = h0 + 2 * wrow + r;
        #pragma unroll
        for (int n = 0; n < 4; ++n) {
          out[(((size_t)(b * 512 + co)) * 64 + h_out) * 64 + n * 16 + l15] = acc[m][r][n][q] * scl;
        }
      }
    }
  }
}

extern "C" void kernel_launch(void* const* d_in, const int* in_sizes, int n_in,
                              void* d_out, int out_size, void* d_ws, size_t ws_size,
                              hipStream_t stream) {
  const float* x      = (const float*)d_in[0];  // (8,512,64,64)
  const float* style  = (const float*)d_in[1];  // (8,512)
  const float* weight = (const float*)d_in[2];  // (1,512,512,3,3)
  const float* mod_w  = (const float*)d_in[3];  // (512,512)
  const float* mod_b  = (const float*)d_in[4];  // (512,)
  float* out = (float*)d_out;

  // workspace layout (~39.4 MB)
  char* ws = (char*)d_ws;
  unsigned short* xT = (unsigned short*)ws;               // 33,554,432 B
  unsigned short* wT = (unsigned short*)(ws + 33554432);  //  4,718,592 B
  float* s     = (float*)(ws + 38273024);                 //     16,384 B
  float* wsq   = (float*)(ws + 38289408);                 //  1,048,576 B
  float* demod = (float*)(ws + 39337984);                 //     16,384 B

  static int lds_set = 0;
  if (!lds_set) {
    (void)hipFuncSetAttribute((const void*)k_conv,
                              hipFuncAttributeMaxDynamicSharedMemorySize, 159232);
    lds_set = 1;
  }

  hipLaunchKernelGGL(k_prep1, dim3(544),  dim3(256), 0, stream,
                     style, mod_w, mod_b, weight, s, wT, wsq);
  hipLaunchKernelGGL(k_prep2, dim3(2064), dim3(256), 0, stream, x, s, wsq, xT, demod);
  hipLaunchKernelGGL(k_conv,  dim3(256),  dim3(512), 159232, stream, xT, wT, demod, out);
}

// Round 13
// 230.314 us; speedup vs baseline: 1.4427x; 1.2562x over previous
//
#include <hip/hip_runtime.h>
#include <hip/hip_bf16.h>
#include <cstdint>
#include <cstddef>

typedef __bf16 bf16x8 __attribute__((ext_vector_type(8)));
typedef float f32x4 __attribute__((ext_vector_type(4)));
typedef unsigned int uintx4 __attribute__((ext_vector_type(4)));

#define CONV_SCALE 0.014731391274719738f   // 1/sqrt(512*9)
#define MOD_SCALE  0.044194173824159216f   // 1/sqrt(512)

__device__ __forceinline__ unsigned short f2bf(float v) {
  unsigned int u = __float_as_uint(v);
  return (unsigned short)((u + 0x7FFFu + ((u >> 16) & 1u)) >> 16);  // RNE
}

__device__ __forceinline__ void gload16(const void* g, void* l) {
  __builtin_amdgcn_global_load_lds(
      (const __attribute__((address_space(1))) unsigned int*)g,
      (__attribute__((address_space(3))) unsigned int*)l, 16, 0, 0);
}

// prep1: blocks 0..511 -> wT + wsq ; blocks 512..543 -> s (modulation)
__global__ void k_prep1(const float* __restrict__ style,
                        const float* __restrict__ mod_w,
                        const float* __restrict__ mod_b,
                        const float* __restrict__ weight,
                        float* __restrict__ s,
                        unsigned short* __restrict__ wT,
                        float* __restrict__ wsq) {
  __shared__ float lds[4608];
  int t = threadIdx.x;             // 256
  if (blockIdx.x < 512) {
    int co = blockIdx.x;
    const float* w = weight + (size_t)co * 4608;
    #pragma unroll
    for (int i = 0; i < 18; ++i) lds[t + i * 256] = w[t + i * 256];
    __syncthreads();
    for (int i = t; i < 576; i += 256) {
      int tap = i / 64, c8 = (i & 63) * 8;
      union { uintx4 v; unsigned short us[8]; } pk;
      #pragma unroll
      for (int j = 0; j < 8; ++j) pk.us[j] = f2bf(lds[(c8 + j) * 9 + tap]);
      *(uintx4*)(wT + ((size_t)tap * 512 + co) * 512 + c8) = pk.v;
    }
    for (int ci = t; ci < 512; ci += 256) {
      float a = 0.f;
      #pragma unroll
      for (int tap = 0; tap < 9; ++tap) { float v = lds[ci * 9 + tap]; a += v * v; }
      wsq[co * 512 + ci] = a * (CONV_SCALE * CONV_SCALE);
    }
  } else {
    int blk = blockIdx.x - 512;    // 0..31
    int b = blk >> 2, ch = blk & 3;
    int ci = ch * 128 + (t >> 1), half = t & 1;
    const float* st = style + b * 512 + half * 256;
    const float* mw = mod_w + (size_t)ci * 512 + half * 256;
    float acc = 0.f;
    #pragma unroll 8
    for (int k = 0; k < 256; k += 4) {
      f32x4 a = *(const f32x4*)(st + k);
      f32x4 m = *(const f32x4*)(mw + k);
      acc += a[0] * m[0] + a[1] * m[1] + a[2] * m[2] + a[3] * m[3];
    }
    acc += __shfl_xor(acc, 1);
    if (half == 0) s[b * 512 + ci] = acc * MOD_SCALE + mod_b[ci];
  }
}

// prep2: blocks 0..2047 -> xT transpose+modulate ; blocks 2048..2063 -> demod
__global__ void k_prep2(const float* __restrict__ x,
                        const float* __restrict__ s,
                        const float* __restrict__ wsq,
                        unsigned short* __restrict__ xT,
                        float* __restrict__ demod) {
  __shared__ float lds[128][68];
  int t = threadIdx.x;             // 256
  int id = blockIdx.x;
  if (id < 2048) {
    int cc = id & 3, h = (id >> 2) & 63, b = id >> 8;
    int w4 = (t & 15) * 4, rr = t >> 4;
    #pragma unroll
    for (int i = 0; i < 8; ++i) {
      int ci = i * 16 + rr;
      *(f32x4*)&lds[ci][w4] =
          *(const f32x4*)&x[(((size_t)(b * 512 + cc * 128 + ci)) * 64 + h) * 64 + w4];
    }
    __syncthreads();
    int pos = t >> 2, c4 = t & 3;
    #pragma unroll
    for (int q = 0; q < 4; ++q) {
      int cb = q * 32 + c4 * 8;
      union { uintx4 v; unsigned short us[8]; } pk;
      #pragma unroll
      for (int j = 0; j < 8; ++j) {
        int ci = cb + j;
        pk.us[j] = f2bf(lds[ci][pos] * s[b * 512 + cc * 128 + ci]);
      }
      *(uintx4*)(xT + (((size_t)(b * 64 + h)) * 64 + pos) * 512 + cc * 128 + cb) = pk.v;
    }
  } else {
    int blk = id - 2048;           // 0..15
    int b = blk >> 1;
    int co = (blk & 1) * 256 + t;
    const float* wq = wsq + (size_t)co * 512;
    const float* sb = s + b * 512;
    float acc = 0.f;
    #pragma unroll 4
    for (int ci = 0; ci < 512; ci += 4) {
      f32x4 q = *(const f32x4*)(wq + ci);
      f32x4 v = *(const f32x4*)(sb + ci);
      acc += q[0] * v[0] * v[0] + q[1] * v[1] * v[1] + q[2] * v[2] * v[2] + q[3] * v[3] * v[3];
    }
    demod[b * 512 + co] = rsqrtf(acc + 1e-8f);
  }
}

// Implicit-GEMM conv — R10 VERBATIM except s_setprio DELETED (single-variable
// A/B: setprio builtins are unmodeled-side-effect instructions = scheduler
// fences between each tap's 12 ds_reads and 32 MFMAs; removing them lets the
// compiler emit fine-grained lgkmcnt so MFMAs start after ~2 reads land).
// Program order read(T)->MFMA(T) per tap is unchanged (no explicit hoisting;
// pressure-aware scheduler bounds live ranges — avoids R11/R12's spills).
// 3-tap phases, gates {3,5,5}, ring-9 slot=tap, 48 barriers.
__global__ __launch_bounds__(512, 2) void k_conv(
    const unsigned short* __restrict__ xT,   // [B][64][64][512]
    const unsigned short* __restrict__ wT,   // [9][512][512]
    const float* __restrict__ demod,         // [B][512]
    float* __restrict__ out) {               // [B][512][64][64]
  extern __shared__ __align__(16) char lds_raw[];
  char* xb0   = lds_raw;              // 42240
  char* xb1   = lds_raw + 42240;      // 42240
  char* wring = lds_raw + 84480;      // 9 * 8192 = 73728
  char* trash = lds_raw + 158208;     // 1024

  const int id  = blockIdx.x;         // 256
  const int g_ord = (id & 7) * 32 + (id >> 3);   // XCD-contiguous ordering
  const int co_t  = g_ord >> 6;       // 0..3
  const int slice = g_ord & 63;       // 0..63
  const int b   = slice >> 3;
  const int h_t = slice & 7;

  const int t = threadIdx.x;          // 512
  const int lane = t & 63, wv = t >> 6;   // 8 waves
  const int h0  = h_t * 8;
  const int co0 = co_t * 128;
  const int l15 = lane & 15, kg = lane >> 4;
  const int wrow = wv & 3;            // row-pair within tile
  const int wco  = wv >> 2;           // co half (0/1)

  // zero both x buffers (halo cols 0/65 + OOB rows stay zero forever)
  {
    uintx4 z = {0u, 0u, 0u, 0u};
    for (int i = t; i < 5280; i += 512) ((uintx4*)lds_raw)[i] = z;
  }
  __syncthreads();

  // ---- x stage: issue j in 0..39 (j = r*4 + k), 1 KB per wave-issue
  auto xstage = [&](int j, int ccs, char* xbuf) {
    int r = j >> 2, k = j & 3;
    int hh = h0 - 1 + r;
    int hc = ((unsigned)hh < 64u) ? hh : 0;
    int p = r * 66 + 1 + k * 16 + (lane >> 2);
    const void* src = xT + (((size_t)(b * 64 + hc)) * 64 + k * 16 + (lane >> 2)) * 512
                      + ccs * 32 + (((lane & 3) ^ ((p >> 1) & 3)) << 3);
    void* dst = ((unsigned)hh < 64u) ? (void*)(xbuf + (r * 66 + 1 + k * 16) * 64)
                                     : (void*)trash;
    gload16(src, dst);
  };
  // ---- w stage for (chunk cc2, tap tap2) into ring slot = tap2 (1 KB/wave-issue)
  auto wstage = [&](int cc2, int tap2) {
    bool valid = (cc2 < 16);
    int cs = valid ? cc2 : 15;
    int row0 = wv * 16;
    int row = row0 + (lane >> 2);
    const void* src = wT + ((size_t)tap2 * 512 + co0 + row) * 512
                      + cs * 32 + (((lane & 3) ^ ((row >> 1) & 3)) << 3);
    void* dst = valid ? (void*)(wring + tap2 * 8192 + row0 * 64) : (void*)trash;
    gload16(src, dst);
  };

  f32x4 acc[4][2][4] = {};            // [m(co)][r(row)][n(w)]

  // one tap: read 4 af (ring slot T) + 8 bfr (xcur), then 32 MFMA — NO fences
  auto dotap = [&](const char* xcur, int T, int dh, int dw) {
    bf16x8 af[4], bfr[2][4];
    #pragma unroll
    for (int m = 0; m < 4; ++m) {
      int row = wco * 64 + m * 16 + l15;
      af[m] = *(const bf16x8*)(wring + T * 8192 + row * 64 + ((kg ^ ((row >> 1) & 3)) << 4));
    }
    #pragma unroll
    for (int r = 0; r < 2; ++r)
      #pragma unroll
      for (int n = 0; n < 4; ++n) {
        int p = (2 * wrow + r + dh) * 66 + n * 16 + l15 + dw;
        bfr[r][n] = *(const bf16x8*)(xcur + p * 64 + ((kg ^ ((p >> 1) & 3)) << 4));
      }
    #pragma unroll
    for (int m = 0; m < 4; ++m)
      #pragma unroll
      for (int r = 0; r < 2; ++r)
        #pragma unroll
        for (int n = 0; n < 4; ++n)
          acc[m][r][n] = __builtin_amdgcn_mfma_f32_16x16x32_bf16(af[m], bfr[r][n], acc[m][r][n], 0, 0, 0);
  };

  // prologue: w slots 0..5 (6/wave), x chunk 0 (5/wave); single full drain.
  #pragma unroll
  for (int i = 0; i < 6; ++i) wstage(0, i);
  #pragma unroll
  for (int i = 0; i < 5; ++i) xstage(wv * 5 + i, 0, xb0);
  asm volatile("s_waitcnt vmcnt(0)" ::: "memory");
  __syncthreads();

  #pragma unroll 1
  for (int cc = 0; cc < 16; ++cc) {
    const char* xcur = (cc & 1) ? xb1 : xb0;
    char* xnxt = (cc & 1) ? xb0 : xb1;
    const int ccs = (cc + 1) & 15;    // wrapped src chunk for next-x (cc=15: dummy)

    // ---- phase 0 (dh=0): reads slots {0,1,2}; stages x(2) + w(cc,6..8)
    asm volatile("s_waitcnt vmcnt(3)" ::: "memory");
    __builtin_amdgcn_s_barrier();
    xstage(wv, ccs, xnxt); xstage(wv + 8, ccs, xnxt);
    wstage(cc, 6); wstage(cc, 7); wstage(cc, 8);
    dotap(xcur, 0, 0, 0); dotap(xcur, 1, 0, 1); dotap(xcur, 2, 0, 2);

    // ---- phase 1 (dh=1): reads slots {3,4,5}; stages x(2) + w(cc+1,0..2)
    asm volatile("s_waitcnt vmcnt(5)" ::: "memory");
    __builtin_amdgcn_s_barrier();
    xstage(wv + 16, ccs, xnxt); xstage(wv + 24, ccs, xnxt);
    wstage(cc + 1, 0); wstage(cc + 1, 1); wstage(cc + 1, 2);
    dotap(xcur, 3, 1, 0); dotap(xcur, 4, 1, 1); dotap(xcur, 5, 1, 2);

    // ---- phase 2 (dh=2): reads slots {6,7,8}; stages x(1, FIRST) + w(cc+1,3..5)
    asm volatile("s_waitcnt vmcnt(5)" ::: "memory");
    __builtin_amdgcn_s_barrier();
    xstage(wv + 32, ccs, xnxt);
    wstage(cc + 1, 3); wstage(cc + 1, 4); wstage(cc + 1, 5);
    dotap(xcur, 6, 2, 0); dotap(xcur, 7, 2, 1); dotap(xcur, 8, 2, 2);
  }

  // epilogue: out[b][co][h][w] = acc * conv_scale * demod[b][co]
  #pragma unroll
  for (int m = 0; m < 4; ++m) {
    #pragma unroll
    for (int q = 0; q < 4; ++q) {
      int co = co0 + wco * 64 + m * 16 + kg * 4 + q;
      float scl = CONV_SCALE * demod[b * 512 + co];
      #pragma unroll
      for (int r = 0; r < 2; ++r) {
        int h_out = h0 + 2 * wrow + r;
        #pragma unroll
        for (int n = 0; n < 4; ++n) {
          out[(((size_t)(b * 512 + co)) * 64 + h_out) * 64 + n * 16 + l15] = acc[m][r][n][q] * scl;
        }
      }
    }
  }
}

extern "C" void kernel_launch(void* const* d_in, const int* in_sizes, int n_in,
                              void* d_out, int out_size, void* d_ws, size_t ws_size,
                              hipStream_t stream) {
  const float* x      = (const float*)d_in[0];  // (8,512,64,64)
  const float* style  = (const float*)d_in[1];  // (8,512)
  const float* weight = (const float*)d_in[2];  // (1,512,512,3,3)
  const float* mod_w  = (const float*)d_in[3];  // (512,512)
  const float* mod_b  = (const float*)d_in[4];  // (512,)
  float* out = (float*)d_out;

  // workspace layout (~39.4 MB)
  char* ws = (char*)d_ws;
  unsigned short* xT = (unsigned short*)ws;               // 33,554,432 B
  unsigned short* wT = (unsigned short*)(ws + 33554432);  //  4,718,592 B
  float* s     = (float*)(ws + 38273024);                 //     16,384 B
  float* wsq   = (float*)(ws + 38289408);                 //  1,048,576 B
  float* demod = (float*)(ws + 39337984);                 //     16,384 B

  static int lds_set = 0;
  if (!lds_set) {
    (void)hipFuncSetAttribute((const void*)k_conv,
                              hipFuncAttributeMaxDynamicSharedMemorySize, 159232);
    lds_set = 1;
  }

  hipLaunchKernelGGL(k_prep1, dim3(544),  dim3(256), 0, stream,
                     style, mod_w, mod_b, weight, s, wT, wsq);
  hipLaunchKernelGGL(k_prep2, dim3(2064), dim3(256), 0, stream, x, s, wsq, xT, demod);
  hipLaunchKernelGGL(k_conv,  dim3(256),  dim3(512), 159232, stream, xT, wT, demod, out);
}

// Round 15
// 162.999 us; speedup vs baseline: 2.0385x; 1.4130x over previous
//
#include <hip/hip_runtime.h>
#include <hip/hip_bf16.h>
#include <cstdint>
#include <cstddef>

typedef __bf16 bf16x8 __attribute__((ext_vector_type(8)));
typedef float f32x4 __attribute__((ext_vector_type(4)));
typedef unsigned int uintx4 __attribute__((ext_vector_type(4)));

#define CONV_SCALE 0.014731391274719738f   // 1/sqrt(512*9)
#define MOD_SCALE  0.044194173824159216f   // 1/sqrt(512)

__device__ __forceinline__ unsigned short f2bf(float v) {
  unsigned int u = __float_as_uint(v);
  return (unsigned short)((u + 0x7FFFu + ((u >> 16) & 1u)) >> 16);  // RNE
}

__device__ __forceinline__ void gload16(const void* g, void* l) {
  __builtin_amdgcn_global_load_lds(
      (const __attribute__((address_space(1))) unsigned int*)g,
      (__attribute__((address_space(3))) unsigned int*)l, 16, 0, 0);
}

// prep1: blocks 0..511 -> wT + wsq ; blocks 512..543 -> s (modulation)
__global__ void k_prep1(const float* __restrict__ style,
                        const float* __restrict__ mod_w,
                        const float* __restrict__ mod_b,
                        const float* __restrict__ weight,
                        float* __restrict__ s,
                        unsigned short* __restrict__ wT,
                        float* __restrict__ wsq) {
  __shared__ float lds[4608];
  int t = threadIdx.x;             // 256
  if (blockIdx.x < 512) {
    int co = blockIdx.x;
    const float* w = weight + (size_t)co * 4608;
    #pragma unroll
    for (int i = 0; i < 18; ++i) lds[t + i * 256] = w[t + i * 256];
    __syncthreads();
    for (int i = t; i < 576; i += 256) {
      int tap = i / 64, c8 = (i & 63) * 8;
      union { uintx4 v; unsigned short us[8]; } pk;
      #pragma unroll
      for (int j = 0; j < 8; ++j) pk.us[j] = f2bf(lds[(c8 + j) * 9 + tap]);
      *(uintx4*)(wT + ((size_t)tap * 512 + co) * 512 + c8) = pk.v;
    }
    for (int ci = t; ci < 512; ci += 256) {
      float a = 0.f;
      #pragma unroll
      for (int tap = 0; tap < 9; ++tap) { float v = lds[ci * 9 + tap]; a += v * v; }
      wsq[co * 512 + ci] = a * (CONV_SCALE * CONV_SCALE);
    }
  } else {
    int blk = blockIdx.x - 512;    // 0..31
    int b = blk >> 2, ch = blk & 3;
    int ci = ch * 128 + (t >> 1), half = t & 1;
    const float* st = style + b * 512 + half * 256;
    const float* mw = mod_w + (size_t)ci * 512 + half * 256;
    float acc = 0.f;
    #pragma unroll 8
    for (int k = 0; k < 256; k += 4) {
      f32x4 a = *(const f32x4*)(st + k);
      f32x4 m = *(const f32x4*)(mw + k);
      acc += a[0] * m[0] + a[1] * m[1] + a[2] * m[2] + a[3] * m[3];
    }
    acc += __shfl_xor(acc, 1);
    if (half == 0) s[b * 512 + ci] = acc * MOD_SCALE + mod_b[ci];
  }
}

// prep2: blocks 0..2047 -> xT transpose+modulate ; blocks 2048..2063 -> demod
__global__ void k_prep2(const float* __restrict__ x,
                        const float* __restrict__ s,
                        const float* __restrict__ wsq,
                        unsigned short* __restrict__ xT,
                        float* __restrict__ demod) {
  __shared__ float lds[128][68];
  __shared__ float s_lds[128];
  int t = threadIdx.x;             // 256
  int id = blockIdx.x;
  if (id < 2048) {
    int cc = id & 3, h = (id >> 2) & 63, b = id >> 8;
    int w4 = (t & 15) * 4, rr = t >> 4;
    if (t < 128) s_lds[t] = s[b * 512 + cc * 128 + t];
    #pragma unroll
    for (int i = 0; i < 8; ++i) {
      int ci = i * 16 + rr;
      *(f32x4*)&lds[ci][w4] =
          *(const f32x4*)&x[(((size_t)(b * 512 + cc * 128 + ci)) * 64 + h) * 64 + w4];
    }
    __syncthreads();
    int pos = t >> 2, c4 = t & 3;
    #pragma unroll
    for (int q = 0; q < 4; ++q) {
      int cb = q * 32 + c4 * 8;
      union { uintx4 v; unsigned short us[8]; } pk;
      #pragma unroll
      for (int j = 0; j < 8; ++j) {
        int ci = cb + j;
        pk.us[j] = f2bf(lds[ci][pos] * s_lds[ci]);
      }
      *(uintx4*)(xT + (((size_t)(b * 64 + h)) * 64 + pos) * 512 + cc * 128 + cb) = pk.v;
    }
  } else {
    int blk = id - 2048;           // 0..15
    int b = blk >> 1;
    int co = (blk & 1) * 256 + t;
    const float* wq = wsq + (size_t)co * 512;
    const float* sb = s + b * 512;
    float acc = 0.f;
    #pragma unroll 4
    for (int ci = 0; ci < 512; ci += 4) {
      f32x4 q = *(const f32x4*)(wq + ci);
      f32x4 v = *(const f32x4*)(sb + ci);
      acc += q[0] * v[0] * v[0] + q[1] * v[1] * v[1] + q[2] * v[2] * v[2] + q[3] * v[3] * v[3];
    }
    demod[b * 512 + co] = rsqrtf(acc + 1e-8f);
  }
}

// Implicit-GEMM conv — R6/R9 structure VERBATIM (best verified: 121-123 µs,
// MfmaUtil 57%, FETCH 79MB, conflicts 0, stable across R6/R9/R10 re-measures).
// 256 blocks (1/CU), 512 thr / 8 waves. Tile: 128co x 8rows x 64w; wave: 64co x 2rows.
// LDS: x dbuf 2*42240 + w 4-slot tap-ring 4*8192 + trash 1024 = 118272 B.
// Per tap-phase g: vmcnt(N) -> ds_read 12 frags (slot g&3 staged at g-2; x[cur]) ->
// issue gload_lds {w for g+2 (1/wave), x for next chunk at taps 1..5 (1/wave)} ->
// raw s_barrier -> setprio(1) 32 MFMA setprio(0).  Loads never drain in main loop;
// per-phase vmcnt gates N(tap) = {1,1,2,2,2,2,2,1,1}.
__global__ __launch_bounds__(512, 2) void k_conv(
    const unsigned short* __restrict__ xT,   // [B][64][64][512]
    const unsigned short* __restrict__ wT,   // [9][512][512]
    const float* __restrict__ demod,         // [B][512]
    float* __restrict__ out) {               // [B][512][64][64]
  extern __shared__ __align__(16) char lds_raw[];
  char* xb0   = lds_raw;              // 42240
  char* xb1   = lds_raw + 42240;      // 42240
  char* wring = lds_raw + 84480;      // 4 * 8192
  char* trash = lds_raw + 117248;     // 1024

  const int id  = blockIdx.x;         // 256
  const int g_ord = (id & 7) * 32 + (id >> 3);   // XCD-contiguous ordering
  const int co_t  = g_ord >> 6;       // 0..3
  const int slice = g_ord & 63;       // 0..63
  const int b   = slice >> 3;
  const int h_t = slice & 7;

  const int t = threadIdx.x;          // 512
  const int lane = t & 63, wv = t >> 6;   // 8 waves
  const int h0  = h_t * 8;
  const int co0 = co_t * 128;
  const int l15 = lane & 15, kg = lane >> 4;
  const int wrow = wv & 3;            // row-pair within tile
  const int wco  = wv >> 2;           // co half (0/1)

  // zero both x buffers (halo cols 0/65 + OOB rows stay zero forever)
  {
    uintx4 z = {0u, 0u, 0u, 0u};
    for (int i = t; i < 5280; i += 512) ((uintx4*)lds_raw)[i] = z;
  }
  __syncthreads();

  // ---- x stage: issue j in 0..39 (j = r*4 + k), 1 KB per wave-issue
  auto xstage = [&](int j, int ccs, char* xbuf) {
    int r = j >> 2, k = j & 3;
    int hh = h0 - 1 + r;
    int hc = ((unsigned)hh < 64u) ? hh : 0;
    int p = r * 66 + 1 + k * 16 + (lane >> 2);
    const void* src = xT + (((size_t)(b * 64 + hc)) * 64 + k * 16 + (lane >> 2)) * 512
                      + ccs * 32 + (((lane & 3) ^ ((p >> 1) & 3)) << 3);
    void* dst = ((unsigned)hh < 64u) ? (void*)(xbuf + (r * 66 + 1 + k * 16) * 64)
                                     : (void*)trash;
    gload16(src, dst);
  };
  // ---- w stage for global tap g (slot g&3): 1 KB per wave-issue (16 rows)
  auto wstage = [&](int g) {
    int gc = (g <= 143) ? g : 143;
    int s = g & 3;
    int cc2 = gc / 9, tap2 = gc - cc2 * 9;
    int row0 = wv * 16;
    int row = row0 + (lane >> 2);
    const void* src = wT + ((size_t)tap2 * 512 + co0 + row) * 512
                      + cc2 * 32 + (((lane & 3) ^ ((row >> 1) & 3)) << 3);
    void* dst = (g <= 143) ? (void*)(wring + s * 8192 + row0 * 64) : (void*)trash;
    gload16(src, dst);
  };

  f32x4 acc[4][2][4] = {};            // [m(co)][r(row)][n(w)]

  // prologue: x[0] fully (5/wave), w slots g=0,1 (1/wave each); drain once.
  #pragma unroll
  for (int i = 0; i < 5; ++i) xstage(wv * 5 + i, 0, xb0);
  wstage(0);
  wstage(1);
  __syncthreads();                    // full drain (once)

  #pragma unroll 1
  for (int cc = 0; cc < 16; ++cc) {
    const char* xcur = (cc & 1) ? xb1 : xb0;
    char* xnxt = (cc & 1) ? xb0 : xb1;
    const int ccs = (cc + 1) & 15;    // wrapped src chunk for next-x (cc=15: dummy)
    #pragma unroll
    for (int tap = 0; tap < 9; ++tap) {
      // 1. counted vmcnt: N = issues(prev phase) = {1,1,2,2,2,2,2,1,1}
      if (tap == 0 || tap == 1 || tap == 7 || tap == 8)
        asm volatile("s_waitcnt vmcnt(1)" ::: "memory");
      else
        asm volatile("s_waitcnt vmcnt(2)" ::: "memory");

      const int g = cc * 9 + tap;
      const int s = g & 3;
      const int dh = tap / 3, dw = tap % 3;

      // 2. ds_read this tap's fragments (w slot staged at g-2; x[cur])
      bf16x8 af[4], bfr[2][4];
      #pragma unroll
      for (int m = 0; m < 4; ++m) {
        int row = wco * 64 + m * 16 + l15;
        af[m] = *(const bf16x8*)(wring + s * 8192 + row * 64 + ((kg ^ ((row >> 1) & 3)) << 4));
      }
      #pragma unroll
      for (int r = 0; r < 2; ++r)
        #pragma unroll
        for (int n = 0; n < 4; ++n) {
          int p = (2 * wrow + r + dh) * 66 + n * 16 + l15 + dw;
          bfr[r][n] = *(const bf16x8*)(xcur + p * 64 + ((kg ^ ((p >> 1) & 3)) << 4));
        }

      // 3. stage issues (stay in flight across barriers)
      wstage(g + 2);
      if (tap >= 1 && tap <= 5) xstage((tap - 1) * 8 + wv, ccs, xnxt);

      // 4. raw barrier (no drain)
      __builtin_amdgcn_s_barrier();

      // 5. MFMA cluster
      __builtin_amdgcn_s_setprio(1);
      #pragma unroll
      for (int m = 0; m < 4; ++m)
        #pragma unroll
        for (int r = 0; r < 2; ++r)
          #pragma unroll
          for (int n = 0; n < 4; ++n)
            acc[m][r][n] = __builtin_amdgcn_mfma_f32_16x16x32_bf16(af[m], bfr[r][n], acc[m][r][n], 0, 0, 0);
      __builtin_amdgcn_s_setprio(0);
    }
  }

  // epilogue: out[b][co][h][w] = acc * conv_scale * demod[b][co]
  #pragma unroll
  for (int m = 0; m < 4; ++m) {
    #pragma unroll
    for (int q = 0; q < 4; ++q) {
      int co = co0 + wco * 64 + m * 16 + kg * 4 + q;
      float scl = CONV_SCALE * demod[b * 512 + co];
      #pragma unroll
      for (int r = 0; r < 2; ++r) {
        int h_out = h0 + 2 * wrow + r;
        #pragma unroll
        for (int n = 0; n < 4; ++n) {
          out[(((size_t)(b * 512 + co)) * 64 + h_out) * 64 + n * 16 + l15] = acc[m][r][n][q] * scl;
        }
      }
    }
  }
}

extern "C" void kernel_launch(void* const* d_in, const int* in_sizes, int n_in,
                              void* d_out, int out_size, void* d_ws, size_t ws_size,
                              hipStream_t stream) {
  const float* x      = (const float*)d_in[0];  // (8,512,64,64)
  const float* style  = (const float*)d_in[1];  // (8,512)
  const float* weight = (const float*)d_in[2];  // (1,512,512,3,3)
  const float* mod_w  = (const float*)d_in[3];  // (512,512)
  const float* mod_b  = (const float*)d_in[4];  // (512,)
  float* out = (float*)d_out;

  // workspace layout (~39.4 MB)
  char* ws = (char*)d_ws;
  unsigned short* xT = (unsigned short*)ws;               // 33,554,432 B
  unsigned short* wT = (unsigned short*)(ws + 33554432);  //  4,718,592 B
  float* s     = (float*)(ws + 38273024);                 //     16,384 B
  float* wsq   = (float*)(ws + 38289408);                 //  1,048,576 B
  float* demod = (float*)(ws + 39337984);                 //     16,384 B

  static int lds_set = 0;
  if (!lds_set) {
    (void)hipFuncSetAttribute((const void*)k_conv,
                              hipFuncAttributeMaxDynamicSharedMemorySize, 118272);
    lds_set = 1;
  }

  hipLaunchKernelGGL(k_prep1, dim3(544),  dim3(256), 0, stream,
                     style, mod_w, mod_b, weight, s, wT, wsq);
  hipLaunchKernelGGL(k_prep2, dim3(2064), dim3(256), 0, stream, x, s, wsq, xT, demod);
  hipLaunchKernelGGL(k_conv,  dim3(256),  dim3(512), 118272, stream, xT, wT, demod, out);
}